// Round 4
// baseline (466.421 us; speedup 1.0000x reference)
//
#include <hip/hip_runtime.h>
#include <hip/hip_bf16.h>
#include <stdint.h>

// CrossAttnBlock: out = softmax((x Wq^T)(cond Wk^T)^T / 8) (cond Wv^T) Wo^T
// B=16 Lq=4096 Lk=77 D=512 Dc=768 H=8 Hd=64.
//
// R4 change: inputs/outputs are FP32 (per reference dtype — the R1-R3 NaN was
// fp32 buffers read as bf16: low-16 mantissa halves decode as bf16 NaN with
// p=1/256). GEMMs convert fp32->bf16 inline during LDS staging; compute stays
// bf16 MFMA; O-projection writes fp32. Workspace tensors (Q/K/V/AO) are bf16.

typedef __bf16 bf16_t;
typedef __bf16 bf16x8 __attribute__((ext_vector_type(8)));
typedef float floatx4 __attribute__((ext_vector_type(4)));

#define MFMA16(a, b, c) __builtin_amdgcn_mfma_f32_16x16x32_bf16((a), (b), (c), 0, 0, 0)

// ---------------------------------------------------------------------------
// C[M,N] = A[M,K] @ B[N,K]^T   (nn.Linear: B is weight [out,in], fp32)
// AF32: A is fp32 (convert during staging) else bf16.
// CF32: C written as fp32 else bf16.
// grid: (N/128, ceil(M/128)), block 256 (4 waves, each computes 64x64)
// ---------------------------------------------------------------------------
template <bool AF32, bool CF32>
__global__ __launch_bounds__(256) void gemm_bt(
    const void* __restrict__ Av, const float* __restrict__ B,
    void* __restrict__ Cv, int M, int N, int K)
{
    __shared__ bf16_t As[128 * 32];   // row-major [128][32], 8 KB
    __shared__ bf16_t Bs[128 * 32];

    const int t = threadIdx.x;
    const int l = t & 63;
    const int w = t >> 6;
    const int wm = w >> 1, wn = w & 1;          // 2x2 wave layout
    const int l15 = l & 15, l4 = l >> 4;
    const int m0 = blockIdx.y * 128, n0 = blockIdx.x * 128;

    floatx4 acc[4][4] = {};

    // staging geometry: 256 threads x 2 iters x 8 elems = 4096 (full tile)
    int rowS[2], colS[2];
#pragma unroll
    for (int i = 0; i < 2; i++) {
        int e = (i * 256 + t) * 8;   // flat elem idx in [128][32] tile
        rowS[i] = e >> 5;
        colS[i] = e & 31;
    }

    for (int k0 = 0; k0 < K; k0 += 32) {
        bf16x8 va[2], vb[2];
#pragma unroll
        for (int i = 0; i < 2; i++) {
            int ra = m0 + rowS[i]; if (ra > M - 1) ra = M - 1;   // clamp (M=1232)
            if (AF32) {
                const float* ap = (const float*)Av + (size_t)ra * K + k0 + colS[i];
                floatx4 f0 = *(const floatx4*)ap;
                floatx4 f1 = *(const floatx4*)(ap + 4);
                bf16x8 v;
#pragma unroll
                for (int e = 0; e < 4; e++) { v[e] = (bf16_t)f0[e]; v[e + 4] = (bf16_t)f1[e]; }
                va[i] = v;
            } else {
                va[i] = *(const bf16x8*)((const bf16_t*)Av + (size_t)ra * K + k0 + colS[i]);
            }
            const float* bp = B + (size_t)(n0 + rowS[i]) * K + k0 + colS[i];
            floatx4 g0 = *(const floatx4*)bp;
            floatx4 g1 = *(const floatx4*)(bp + 4);
            bf16x8 wv;
#pragma unroll
            for (int e = 0; e < 4; e++) { wv[e] = (bf16_t)g0[e]; wv[e + 4] = (bf16_t)g1[e]; }
            vb[i] = wv;
        }
#pragma unroll
        for (int i = 0; i < 2; i++) {
            *(bf16x8*)&As[(i * 256 + t) * 8] = va[i];
            *(bf16x8*)&Bs[(i * 256 + t) * 8] = vb[i];
        }
        __syncthreads();

        bf16x8 af[4], bfr[4];
#pragma unroll
        for (int i = 0; i < 4; i++)
            af[i] = *(const bf16x8*)&As[(wm * 64 + i * 16 + l15) * 32 + l4 * 8];
#pragma unroll
        for (int j = 0; j < 4; j++)
            bfr[j] = *(const bf16x8*)&Bs[(wn * 64 + j * 16 + l15) * 32 + l4 * 8];
#pragma unroll
        for (int i = 0; i < 4; i++)
#pragma unroll
            for (int j = 0; j < 4; j++)
                acc[i][j] = MFMA16(af[i], bfr[j], acc[i][j]);
        __syncthreads();
    }

    // epilogue: C/D layout col=lane&15, row=(lane>>4)*4+reg
#pragma unroll
    for (int i = 0; i < 4; i++)
#pragma unroll
        for (int j = 0; j < 4; j++)
#pragma unroll
            for (int r = 0; r < 4; r++) {
                int row = m0 + wm * 64 + i * 16 + l4 * 4 + r;
                int col = n0 + wn * 64 + j * 16 + l15;
                if (row < M) {
                    if (CF32) ((float*)Cv)[(size_t)row * N + col] = acc[i][j][r];
                    else ((bf16_t*)Cv)[(size_t)row * N + col] = (bf16_t)acc[i][j][r];
                }
            }
}

// ---------------------------------------------------------------------------
// Fused attention, IN-PLACE on QO (bf16 workspace): reads Q slice into regs,
// writes O to the same slice. Disjoint across blocks.
// grid: (Lq/64, B*H), block 256; wave w handles q-rows q0+16w..+16.
// ---------------------------------------------------------------------------
#define LK 77
#define KSTR 72    // Ks row stride (2-way bank aliasing only — free)
#define VSTR 104   // Vt / Ps row stride
#define JP 96      // j padded to 3 MFMA k-steps

__global__ __launch_bounds__(256) void attn_fused(
    bf16_t* QO,                              // aliased read+write, no restrict
    const bf16_t* __restrict__ Kg,
    const bf16_t* __restrict__ Vg)
{
    __shared__ bf16_t Ks[80 * KSTR];        // K rows [j][d], rows 77..79 zeroed
    __shared__ bf16_t Vs[64 * VSTR];        // V^T [d][j], j>=77 zeroed
    __shared__ bf16_t Ps[4 * 16 * VSTR];    // per-wave P [16][96+pad]

    const int t = threadIdx.x;
    const int w = t >> 6, l = t & 63;
    const int l15 = l & 15, l4 = l >> 4;
    const int b = blockIdx.y >> 3, h = blockIdx.y & 7;
    const int q0 = blockIdx.x * 64;

    // --- stage K rows (vector 16B) ---
    for (int idx = t; idx < LK * 8; idx += 256) {
        int j = idx >> 3, c = (idx & 7) * 8;
        *(uint4*)&Ks[j * KSTR + c] =
            *(const uint4*)&Kg[((size_t)(b * LK + j)) * 512 + h * 64 + c];
    }
    for (int idx = t; idx < 3 * KSTR; idx += 256)   // zero pad rows 77..79
        Ks[LK * KSTR + idx] = (bf16_t)0.0f;

    // --- stage V transposed ---
    for (int idx = t; idx < LK * 64; idx += 256) {
        int j = idx >> 6, d = idx & 63;
        Vs[d * VSTR + j] = Vg[((size_t)(b * LK + j)) * 512 + h * 64 + d];
    }
    for (int idx = t; idx < 64 * (JP - LK); idx += 256) {
        int d = idx / (JP - LK), j = LK + idx % (JP - LK);
        Vs[d * VSTR + j] = (bf16_t)0.0f;
    }
    __syncthreads();

    // --- Q fragments from global (A-layout: m=lane&15, k=(lane>>4)*8) ---
    const bf16_t* qbase =
        QO + ((size_t)(b * 4096 + q0 + w * 16 + l15)) * 512 + h * 64 + l4 * 8;
    bf16x8 aq0 = *(const bf16x8*)qbase;
    bf16x8 aq1 = *(const bf16x8*)(qbase + 32);

    // --- S = Q K^T (5 col-tiles of 16, 2 k-steps) ---
    floatx4 s[5];
#pragma unroll
    for (int n = 0; n < 5; n++) {
        floatx4 z = {0.f, 0.f, 0.f, 0.f};
        bf16x8 b0 = *(const bf16x8*)&Ks[(n * 16 + l15) * KSTR + l4 * 8];
        bf16x8 b1 = *(const bf16x8*)&Ks[(n * 16 + l15) * KSTR + 32 + l4 * 8];
        z = MFMA16(aq0, b0, z);
        z = MFMA16(aq1, b1, z);
        s[n] = z;
    }

    // --- in-register softmax (row r lives across the 16 lanes sharing l>>4) ---
    const float scale = 0.125f;   // 64^-0.5
    float p[5][4], linv[4];
#pragma unroll
    for (int r = 0; r < 4; r++) {
        float smax = -1e30f;
#pragma unroll
        for (int n = 0; n < 5; n++) {
            float v = s[n][r] * scale;
            if (n == 4 && (64 + l15) >= LK) v = -1e30f;   // mask j>=77
            p[n][r] = v;
            smax = fmaxf(smax, v);
        }
#pragma unroll
        for (int off = 1; off < 16; off <<= 1)
            smax = fmaxf(smax, __shfl_xor(smax, off, 64));
        float sum = 0.f;
#pragma unroll
        for (int n = 0; n < 5; n++) {
            float e = __expf(p[n][r] - smax);
            p[n][r] = e;
            sum += e;
        }
#pragma unroll
        for (int off = 1; off < 16; off <<= 1)
            sum += __shfl_xor(sum, off, 64);
        linv[r] = 1.0f / sum;
    }

    // --- write normalized P to LDS (C-layout -> A-layout transform) ---
    bf16_t* pw = Ps + w * 16 * VSTR;
#pragma unroll
    for (int r = 0; r < 4; r++) {
        int row = l4 * 4 + r;
#pragma unroll
        for (int n = 0; n < 5; n++)
            pw[row * VSTR + n * 16 + l15] = (bf16_t)(p[n][r] * linv[r]);
        pw[row * VSTR + 80 + l15] = (bf16_t)0.0f;     // zero j=80..95
    }
    __syncthreads();

    // --- O = P V (4 d-tiles, 3 k-steps over padded j=96), in-place over Q ---
    bf16x8 ap[3];
#pragma unroll
    for (int ks = 0; ks < 3; ks++)
        ap[ks] = *(const bf16x8*)&pw[l15 * VSTR + ks * 32 + l4 * 8];
#pragma unroll
    for (int n2 = 0; n2 < 4; n2++) {
        floatx4 o = {0.f, 0.f, 0.f, 0.f};
#pragma unroll
        for (int ks = 0; ks < 3; ks++) {
            bf16x8 bv = *(const bf16x8*)&Vs[(n2 * 16 + l15) * VSTR + ks * 32 + l4 * 8];
            o = MFMA16(ap[ks], bv, o);
        }
#pragma unroll
        for (int r = 0; r < 4; r++) {
            int q = q0 + w * 16 + l4 * 4 + r;
            QO[((size_t)(b * 4096 + q)) * 512 + h * 64 + n2 * 16 + l15] = (bf16_t)o[r];
        }
    }
}

// ---------------------------------------------------------------------------
extern "C" void kernel_launch(void* const* d_in, const int* in_sizes, int n_in,
                              void* d_out, int out_size, void* d_ws, size_t ws_size,
                              hipStream_t stream)
{
    const float* x    = (const float*)d_in[0];  // [16,4096,512] fp32
    const float* cond = (const float*)d_in[1];  // [16,77,768]   fp32
    const float* w_q  = (const float*)d_in[2];  // [512,512]     fp32
    const float* w_k  = (const float*)d_in[3];  // [512,768]     fp32
    const float* w_v  = (const float*)d_in[4];  // [512,768]     fp32
    const float* w_o  = (const float*)d_in[5];  // [512,512]     fp32
    float* out = (float*)d_out;                 // [16,4096,512] fp32

    const int Mq  = 16 * 4096;   // 65536
    const int Mkv = 16 * 77;     // 1232

    // workspace (bf16): Q/AO shared 67.1MB | K 1.26MB | V 1.26MB  (~69.7 MB)
    bf16_t* Qb = (bf16_t*)d_ws;
    bf16_t* Kb = Qb + (size_t)Mq * 512;
    bf16_t* Vb = Kb + (size_t)Mkv * 512;

    gemm_bt<true,  false><<<dim3(4, Mq / 128), 256, 0, stream>>>(x, w_q, Qb, Mq, 512, 512);
    gemm_bt<true,  false><<<dim3(4, (Mkv + 127) / 128), 256, 0, stream>>>(cond, w_k, Kb, Mkv, 512, 768);
    gemm_bt<true,  false><<<dim3(4, (Mkv + 127) / 128), 256, 0, stream>>>(cond, w_v, Vb, Mkv, 512, 768);
    attn_fused<<<dim3(64, 128), 256, 0, stream>>>(Qb, Kb, Vb);   // Q -> AO in place
    gemm_bt<false, true ><<<dim3(4, Mq / 128), 256, 0, stream>>>(Qb, w_o, out, Mq, 512, 512);
}